// Round 1
// baseline (156.181 us; speedup 1.0000x reference)
//
#include <hip/hip_runtime.h>

constexpr int CH = 128;
constexpr int HH = 48, WW = 48;
constexpr int PP = HH * WW;        // 2304
constexpr int NPIX = 2 * PP;       // 4608
constexpr int K2 = 169;            // 13x13 window

// workspace layout (in floats)
constexpr size_t OFF_XT = 0;                               // [NPIX][CH] pixel-major x
constexpr size_t OFF_EN = OFF_XT + (size_t)NPIX * CH;      // [NPIX][CH] enhanced
constexpr size_t OFF_XD = OFF_EN + (size_t)NPIX * CH;      // [2*576][CH] downsampled
constexpr size_t OFF_RN = OFF_XD + (size_t)2 * 576 * CH;   // [NPIX] 1/max(||x||,eps)
constexpr size_t OFF_DF = OFF_RN + NPIX;                   // [NPIX] df
constexpr size_t OFF_MM = OFF_DF + NPIX;                   // [4] uint min/max per batch
constexpr size_t OFF_GN = OFF_MM + 4;                      // [64*2] mu,rstd
constexpr size_t WS_FLOATS = OFF_GN + 128;

__device__ __forceinline__ int refl(int t) {
    return t < 0 ? -t : (t > 47 ? 94 - t : t);
}

// ---- transpose x [B,C,H,W] -> xt [B*P][C]; init minmax slots -------------
__global__ __launch_bounds__(256) void k_tr(const float* __restrict__ x,
                                            float* __restrict__ xt,
                                            unsigned* __restrict__ mm) {
    __shared__ float t[128][65];
    const int tid = threadIdx.x;
    const int p0 = blockIdx.x * 64;          // 72 blocks, 64 pixels each
    const int b = p0 / PP, pb = p0 % PP;
    const int pl = tid & 63, cb = tid >> 6;
    const float* xb = x + (size_t)b * CH * PP + pb + pl;
#pragma unroll
    for (int r = 0; r < 32; r++) {
        int c = r * 4 + cb;
        t[c][pl] = xb[(size_t)c * PP];
    }
    __syncthreads();
    const int c4 = tid & 31, pq = tid >> 5;
#pragma unroll
    for (int r = 0; r < 8; r++) {
        int pp = r * 8 + pq;
        float4 v = make_float4(t[c4 * 4][pp], t[c4 * 4 + 1][pp],
                               t[c4 * 4 + 2][pp], t[c4 * 4 + 3][pp]);
        ((float4*)(xt + ((size_t)(p0 + pp)) * CH))[c4] = v;
    }
    if (blockIdx.x == 0 && tid < 4) mm[tid] = (tid & 1) ? 0u : 0x7f800000u;
}

// ---- downsample 48x48 -> 24x24 (exact 2x2 average) -----------------------
__global__ __launch_bounds__(256) void k_down(const float* __restrict__ xt,
                                              float* __restrict__ xdt) {
    int t = blockIdx.x * 256 + threadIdx.x;  // 144 blocks: 2*576*32 exactly
    int c4 = t & 31, rest = t >> 5;
    int xp = rest % 24, yp = (rest / 24) % 24, b = rest / 576;
    const float4* r0 = (const float4*)(xt + ((size_t)(b * PP + (2 * yp) * WW + 2 * xp)) * CH);
    const float4* r2 = (const float4*)(xt + ((size_t)(b * PP + (2 * yp + 1) * WW + 2 * xp)) * CH);
    float4 a = r0[c4], bb = r0[32 + c4], c = r2[c4], d = r2[32 + c4];
    float4 o;
    o.x = 0.25f * (a.x + bb.x + c.x + d.x);
    o.y = 0.25f * (a.y + bb.y + c.y + d.y);
    o.z = 0.25f * (a.z + bb.z + c.z + d.z);
    o.w = 0.25f * (a.w + bb.w + c.w + d.w);
    ((float4*)(xdt + ((size_t)(b * 576 + yp * 24 + xp)) * CH))[c4] = o;
}

// ---- df (bilinear upsample + L1 over C), pixel norms, per-batch min/max --
__global__ __launch_bounds__(256) void k_df(const float* __restrict__ xt,
                                            const float* __restrict__ xdt,
                                            float* __restrict__ df,
                                            float* __restrict__ rn,
                                            unsigned* __restrict__ mm) {
    __shared__ float dfl[16];
    const int wv = threadIdx.x >> 6, lane = threadIdx.x & 63;
#pragma unroll
    for (int it = 0; it < 4; ++it) {
        const int pl = it * 4 + wv;
        const int pix = blockIdx.x * 16 + pl;   // 288 blocks * 16 px
        const int b = pix / PP, p = pix % PP;
        const int h = p / WW, w = p % WW;
        float py = 0.5f * h - 0.25f; int y0 = (int)floorf(py); float fy = py - (float)y0;
        float px = 0.5f * w - 0.25f; int x0 = (int)floorf(px); float fx = px - (float)x0;
        int y0c = max(y0, 0), y1c = min(y0 + 1, 23);
        int x0c = max(x0, 0), x1c = min(x0 + 1, 23);
        const float2* v00 = (const float2*)(xdt + ((size_t)(b * 576 + y0c * 24 + x0c)) * CH);
        const float2* v01 = (const float2*)(xdt + ((size_t)(b * 576 + y0c * 24 + x1c)) * CH);
        const float2* v10 = (const float2*)(xdt + ((size_t)(b * 576 + y1c * 24 + x0c)) * CH);
        const float2* v11 = (const float2*)(xdt + ((size_t)(b * 576 + y1c * 24 + x1c)) * CH);
        const float2* xr = (const float2*)(xt + (size_t)pix * CH);
        float w00 = (1.f - fy) * (1.f - fx), w01 = (1.f - fy) * fx;
        float w10 = fy * (1.f - fx), w11 = fy * fx;
        float2 a = v00[lane], bq = v01[lane], c = v10[lane], d = v11[lane], xv = xr[lane];
        float ux = w00 * a.x + w01 * bq.x + w10 * c.x + w11 * d.x;
        float uy = w00 * a.y + w01 * bq.y + w10 * c.y + w11 * d.y;
        float ds = fabsf(xv.x - ux) + fabsf(xv.y - uy);
        float ss = xv.x * xv.x + xv.y * xv.y;
#pragma unroll
        for (int s = 32; s; s >>= 1) { ds += __shfl_xor(ds, s); ss += __shfl_xor(ss, s); }
        if (lane == 0) {
            df[pix] = ds;
            rn[pix] = 1.f / fmaxf(sqrtf(ss), 1e-12f);
            dfl[pl] = ds;
        }
    }
    __syncthreads();
    if (threadIdx.x == 0) {
        float mn = dfl[0], mx = dfl[0];
#pragma unroll
        for (int i = 1; i < 16; i++) { mn = fminf(mn, dfl[i]); mx = fmaxf(mx, dfl[i]); }
        const int b = (blockIdx.x * 16) / PP;   // 16 | 2304, no straddle
        atomicMin(&mm[b * 2], __float_as_uint(mn));
        atomicMax(&mm[b * 2 + 1], __float_as_uint(mx));
    }
}

// ---- GroupNorm stats: 64 blocks = (b,g) ----------------------------------
__global__ __launch_bounds__(256) void k_gn(const float* __restrict__ xt,
                                            float* __restrict__ gnb) {
    const int b = blockIdx.x >> 5, g = blockIdx.x & 31;
    const int tid = threadIdx.x;
    float s = 0.f, sq = 0.f;
    for (int p = tid; p < PP; p += 256) {
        float4 v = *(const float4*)(xt + ((size_t)(b * PP + p)) * CH + g * 4);
        s += v.x + v.y + v.z + v.w;
        sq += v.x * v.x + v.y * v.y + v.z * v.z + v.w * v.w;
    }
    __shared__ float rs[256], rq[256];
    rs[tid] = s; rq[tid] = sq;
    __syncthreads();
    for (int st = 128; st; st >>= 1) {
        if (tid < st) { rs[tid] += rs[tid + st]; rq[tid] += rq[tid + st]; }
        __syncthreads();
    }
    if (tid == 0) {
        float mu = rs[0] / 9216.f;
        float var = rq[0] / 9216.f - mu * mu;
        gnb[blockIdx.x * 2] = mu;
        gnb[blockIdx.x * 2 + 1] = 1.f / sqrtf(var + 1e-5f);
    }
}

// ---- main IPG: one wave per pixel (4 px / block) -------------------------
__global__ __launch_bounds__(256) void k_main(const float* __restrict__ xt,
                                              const float* __restrict__ rn,
                                              const float* __restrict__ df,
                                              const unsigned* __restrict__ mm,
                                              const float* __restrict__ gnb,
                                              const float* __restrict__ gamma,
                                              const float* __restrict__ beta,
                                              float* __restrict__ en) {
    __shared__ float xc[4][CH];
    __shared__ float sw[4][K2];
    const int wv = threadIdx.x >> 6, lane = threadIdx.x & 63;
    const int pix = blockIdx.x * 4 + wv;      // 1152 blocks
    const int b = pix / PP, p = pix % PP;
    const int h = p / WW, w = p % WW;

    float2 xv = ((const float2*)(xt + (size_t)pix * CH))[lane];
    ((float2*)xc[wv])[lane] = xv;
    __syncthreads();

    // connection count
    const float dmin = __uint_as_float(mm[b * 2]);
    const float dmax = __uint_as_float(mm[b * 2 + 1]);
    const float dn = (df[pix] - dmin) / (dmax - dmin + 1e-8f);
    const int cc = 1 + (int)rintf(dn * 15.f);  // round-half-even matches jnp.round
    const float rnp = rn[pix];

    // sims: lane owns offsets k, k+64, k+128
    float sk[3];
    const float4* xc4 = (const float4*)xc[wv];
#pragma unroll
    for (int r = 0; r < 3; r++) {
        const int k = r * 64 + lane;
        float s = -1e30f;
        if (k < K2) {
            int ki = k / 13;
            int yy = refl(h + ki - 6);
            int xx = refl(w + (k - ki * 13) - 6);
            int p2 = yy * WW + xx;
            const float4* q = (const float4*)(xt + ((size_t)(b * PP + p2)) * CH);
            float dot = 0.f;
#pragma unroll 8
            for (int c4 = 0; c4 < 32; c4++) {
                float4 av = q[c4], bv = xc4[c4];
                dot += av.x * bv.x + av.y * bv.y + av.z * bv.z + av.w * bv.w;
            }
            s = dot * rnp * rn[b * PP + p2];
            sw[wv][k] = s;
        }
        sk[r] = s;
    }
    __syncthreads();

    // stable descending ranks
    int rk[3] = {0, 0, 0};
    for (int j = 0; j < K2; j++) {
        float sj = sw[wv][j];
#pragma unroll
        for (int r = 0; r < 3; r++) {
            int k = r * 64 + lane;
            rk[r] += (sj > sk[r]) || (sj == sk[r] && j < k);
        }
    }
    __syncthreads();

    // weights (exp * mask), overwrite sim storage
    float wpart = 0.f;
#pragma unroll
    for (int r = 0; r < 3; r++) {
        int k = r * 64 + lane;
        if (k < K2) {
            float v = (rk[r] < cc) ? expf(sk[r]) : 0.f;
            sw[wv][k] = v;
            wpart += v;
        }
    }
#pragma unroll
    for (int s = 32; s; s >>= 1) wpart += __shfl_xor(wpart, s);
    const float invw = 1.f / wpart;
    __syncthreads();

    // sparse weighted gather: only ~cc (<=16) of 169 weights are nonzero
    float2 acc = make_float2(0.f, 0.f);
    for (int k = 0; k < K2; k++) {
        float wk = sw[wv][k];
        if (wk != 0.f) {
            int ki = k / 13;
            int yy = refl(h + ki - 6);
            int xx = refl(w + (k - ki * 13) - 6);
            float2 v = ((const float2*)(xt + ((size_t)(b * PP + yy * WW + xx)) * CH))[lane];
            acc.x += wk * v.x;
            acc.y += wk * v.y;
        }
    }

    // GroupNorm + residual-into-enhanced
    const int c0 = lane * 2;
    const int g = lane >> 1;
    const float mu = gnb[(b * 32 + g) * 2], rstd = gnb[(b * 32 + g) * 2 + 1];
    float e0 = acc.x * invw + (xv.x - mu) * rstd * gamma[c0] + beta[c0];
    float e1 = acc.y * invw + (xv.y - mu) * rstd * gamma[c0 + 1] + beta[c0 + 1];
    ((float2*)(en + (size_t)pix * CH))[lane] = make_float2(e0, e1);
}

// ---- FFN: out = enhanced + (w2 @ relu(w1 @ enhanced + b1) + b2) ----------
__global__ __launch_bounds__(256) void k_ffn(const float* __restrict__ en,
                                             const float* __restrict__ w1,
                                             const float* __restrict__ b1,
                                             const float* __restrict__ w2,
                                             const float* __restrict__ b2,
                                             float* __restrict__ out) {
    __shared__ float elds[32][CH];     // 16 KB
    __shared__ float hlds[32][256];    // 32 KB
    const int tid = threadIdx.x;
    const int p0 = blockIdx.x * 32;    // 144 blocks, 32 px each (no batch straddle)
    const int b = p0 / PP, pb = p0 % PP;
    {
        const float4* src = (const float4*)(en + (size_t)p0 * CH);
        float4* dst = (float4*)&elds[0][0];
#pragma unroll
        for (int r = 0; r < 4; r++) dst[r * 256 + tid] = src[r * 256 + tid];
    }
    __syncthreads();
    {   // h[o] for all 32 px; thread = o
        const int o = tid;
        float acc[32];
#pragma unroll
        for (int i = 0; i < 32; i++) acc[i] = 0.f;
        const float4* wr = (const float4*)(w1 + (size_t)o * CH);
        for (int c4 = 0; c4 < 32; c4++) {
            float4 wvv = wr[c4];
#pragma unroll
            for (int px = 0; px < 32; px++) {
                float4 ev = *(const float4*)&elds[px][c4 * 4];  // LDS broadcast
                acc[px] += wvv.x * ev.x + wvv.y * ev.y + wvv.z * ev.z + wvv.w * ev.w;
            }
        }
        float bv = b1[o];
#pragma unroll
        for (int px = 0; px < 32; px++) hlds[px][o] = fmaxf(acc[px] + bv, 0.f);
    }
    __syncthreads();
    {   // ffn + residual; thread = (c, half)
        const int c = tid & 127, half = tid >> 7;
        const int px0 = half * 16;
        float acc[16];
#pragma unroll
        for (int i = 0; i < 16; i++) acc[i] = 0.f;
        const float4* wr = (const float4*)(w2 + (size_t)c * 256);
        for (int o4 = 0; o4 < 64; o4++) {
            float4 wvv = wr[o4];
#pragma unroll
            for (int i = 0; i < 16; i++) {
                float4 hv = *(const float4*)&hlds[px0 + i][o4 * 4];  // LDS broadcast
                acc[i] += wvv.x * hv.x + wvv.y * hv.y + wvv.z * hv.z + wvv.w * hv.w;
            }
        }
        float bv = b2[c];
        float* obase = out + ((size_t)(b * CH + c)) * PP + pb + px0;
#pragma unroll
        for (int r = 0; r < 4; r++) {
            float4 v;
            v.x = elds[px0 + r * 4 + 0][c] + acc[r * 4 + 0] + bv;
            v.y = elds[px0 + r * 4 + 1][c] + acc[r * 4 + 1] + bv;
            v.z = elds[px0 + r * 4 + 2][c] + acc[r * 4 + 2] + bv;
            v.w = elds[px0 + r * 4 + 3][c] + acc[r * 4 + 3] + bv;
            *(float4*)(obase + r * 4) = v;
        }
    }
}

extern "C" void kernel_launch(void* const* d_in, const int* in_sizes, int n_in,
                              void* d_out, int out_size, void* d_ws, size_t ws_size,
                              hipStream_t stream) {
    (void)in_sizes; (void)n_in; (void)out_size;
    if (ws_size < WS_FLOATS * sizeof(float)) return;  // would corrupt; fail visibly

    const float* x     = (const float*)d_in[0];
    const float* gamma = (const float*)d_in[1];
    const float* beta  = (const float*)d_in[2];
    const float* w1    = (const float*)d_in[3];
    const float* b1    = (const float*)d_in[4];
    const float* w2    = (const float*)d_in[5];
    const float* b2    = (const float*)d_in[6];
    float* ws = (float*)d_ws;
    float* xt   = ws + OFF_XT;
    float* en   = ws + OFF_EN;
    float* xdt  = ws + OFF_XD;
    float* rn   = ws + OFF_RN;
    float* df   = ws + OFF_DF;
    unsigned* mm = (unsigned*)(ws + OFF_MM);
    float* gnb  = ws + OFF_GN;
    float* out  = (float*)d_out;

    hipLaunchKernelGGL(k_tr,   dim3(72),   dim3(256), 0, stream, x, xt, mm);
    hipLaunchKernelGGL(k_down, dim3(144),  dim3(256), 0, stream, xt, xdt);
    hipLaunchKernelGGL(k_df,   dim3(288),  dim3(256), 0, stream, xt, xdt, df, rn, mm);
    hipLaunchKernelGGL(k_gn,   dim3(64),   dim3(256), 0, stream, xt, gnb);
    hipLaunchKernelGGL(k_main, dim3(1152), dim3(256), 0, stream, xt, rn, df, mm, gnb, gamma, beta, en);
    hipLaunchKernelGGL(k_ffn,  dim3(144),  dim3(256), 0, stream, en, w1, b1, w2, b2, out);
}

// Round 2
// 102.673 us; speedup vs baseline: 1.5211x; 1.5211x over previous
//
#include <hip/hip_runtime.h>

constexpr int CH = 128;
constexpr int HH = 48, WW = 48;
constexpr int PP = HH * WW;        // 2304
constexpr int NPIX = 2 * PP;       // 4608
constexpr int K2 = 169;            // 13x13 window

// workspace layout (in floats)
constexpr size_t OFF_XT = 0;                               // [NPIX][CH] pixel-major x
constexpr size_t OFF_EN = OFF_XT + (size_t)NPIX * CH;      // [NPIX][CH] enhanced
constexpr size_t OFF_XD = OFF_EN + (size_t)NPIX * CH;      // [2*576][CH] downsampled
constexpr size_t OFF_RN = OFF_XD + (size_t)2 * 576 * CH;   // [NPIX] 1/max(||x||,eps)
constexpr size_t OFF_DF = OFF_RN + NPIX;                   // [NPIX] df
constexpr size_t OFF_MM = OFF_DF + NPIX;                   // [4] uint min/max per batch
constexpr size_t OFF_GN = OFF_MM + 4;                      // [64*2] mu,rstd
constexpr size_t WS_FLOATS = OFF_GN + 128;

__device__ __forceinline__ int refl(int t) {
    return t < 0 ? -t : (t > 47 ? 94 - t : t);
}

// ---- transpose x [B,C,H,W] -> xt [B*P][C]; init minmax slots -------------
__global__ __launch_bounds__(256) void k_tr(const float* __restrict__ x,
                                            float* __restrict__ xt,
                                            unsigned* __restrict__ mm) {
    __shared__ float t[128][65];
    const int tid = threadIdx.x;
    const int p0 = blockIdx.x * 64;          // 72 blocks, 64 pixels each
    const int b = p0 / PP, pb = p0 % PP;
    const int pl = tid & 63, cb = tid >> 6;
    const float* xb = x + (size_t)b * CH * PP + pb + pl;
#pragma unroll
    for (int r = 0; r < 32; r++) {
        int c = r * 4 + cb;
        t[c][pl] = xb[(size_t)c * PP];
    }
    __syncthreads();
    const int c4 = tid & 31, pq = tid >> 5;
#pragma unroll
    for (int r = 0; r < 8; r++) {
        int pp = r * 8 + pq;
        float4 v = make_float4(t[c4 * 4][pp], t[c4 * 4 + 1][pp],
                               t[c4 * 4 + 2][pp], t[c4 * 4 + 3][pp]);
        ((float4*)(xt + ((size_t)(p0 + pp)) * CH))[c4] = v;
    }
    if (blockIdx.x == 0 && tid < 4) mm[tid] = (tid & 1) ? 0u : 0x7f800000u;
}

// ---- downsample 48x48 -> 24x24 (exact 2x2 average) -----------------------
__global__ __launch_bounds__(256) void k_down(const float* __restrict__ xt,
                                              float* __restrict__ xdt) {
    int t = blockIdx.x * 256 + threadIdx.x;  // 144 blocks: 2*576*32 exactly
    int c4 = t & 31, rest = t >> 5;
    int xp = rest % 24, yp = (rest / 24) % 24, b = rest / 576;
    const float4* r0 = (const float4*)(xt + ((size_t)(b * PP + (2 * yp) * WW + 2 * xp)) * CH);
    const float4* r2 = (const float4*)(xt + ((size_t)(b * PP + (2 * yp + 1) * WW + 2 * xp)) * CH);
    float4 a = r0[c4], bb = r0[32 + c4], c = r2[c4], d = r2[32 + c4];
    float4 o;
    o.x = 0.25f * (a.x + bb.x + c.x + d.x);
    o.y = 0.25f * (a.y + bb.y + c.y + d.y);
    o.z = 0.25f * (a.z + bb.z + c.z + d.z);
    o.w = 0.25f * (a.w + bb.w + c.w + d.w);
    ((float4*)(xdt + ((size_t)(b * 576 + yp * 24 + xp)) * CH))[c4] = o;
}

// ---- df (bilinear upsample + L1 over C), pixel norms, per-batch min/max --
__global__ __launch_bounds__(256) void k_df(const float* __restrict__ xt,
                                            const float* __restrict__ xdt,
                                            float* __restrict__ df,
                                            float* __restrict__ rn,
                                            unsigned* __restrict__ mm) {
    __shared__ float dfl[16];
    const int wv = threadIdx.x >> 6, lane = threadIdx.x & 63;
#pragma unroll
    for (int it = 0; it < 4; ++it) {
        const int pl = it * 4 + wv;
        const int pix = blockIdx.x * 16 + pl;   // 288 blocks * 16 px
        const int b = pix / PP, p = pix % PP;
        const int h = p / WW, w = p % WW;
        float py = 0.5f * h - 0.25f; int y0 = (int)floorf(py); float fy = py - (float)y0;
        float px = 0.5f * w - 0.25f; int x0 = (int)floorf(px); float fx = px - (float)x0;
        int y0c = max(y0, 0), y1c = min(y0 + 1, 23);
        int x0c = max(x0, 0), x1c = min(x0 + 1, 23);
        const float2* v00 = (const float2*)(xdt + ((size_t)(b * 576 + y0c * 24 + x0c)) * CH);
        const float2* v01 = (const float2*)(xdt + ((size_t)(b * 576 + y0c * 24 + x1c)) * CH);
        const float2* v10 = (const float2*)(xdt + ((size_t)(b * 576 + y1c * 24 + x0c)) * CH);
        const float2* v11 = (const float2*)(xdt + ((size_t)(b * 576 + y1c * 24 + x1c)) * CH);
        const float2* xr = (const float2*)(xt + (size_t)pix * CH);
        float w00 = (1.f - fy) * (1.f - fx), w01 = (1.f - fy) * fx;
        float w10 = fy * (1.f - fx), w11 = fy * fx;
        float2 a = v00[lane], bq = v01[lane], c = v10[lane], d = v11[lane], xv = xr[lane];
        float ux = w00 * a.x + w01 * bq.x + w10 * c.x + w11 * d.x;
        float uy = w00 * a.y + w01 * bq.y + w10 * c.y + w11 * d.y;
        float ds = fabsf(xv.x - ux) + fabsf(xv.y - uy);
        float ss = xv.x * xv.x + xv.y * xv.y;
#pragma unroll
        for (int s = 32; s; s >>= 1) { ds += __shfl_xor(ds, s); ss += __shfl_xor(ss, s); }
        if (lane == 0) {
            df[pix] = ds;
            rn[pix] = 1.f / fmaxf(sqrtf(ss), 1e-12f);
            dfl[pl] = ds;
        }
    }
    __syncthreads();
    if (threadIdx.x == 0) {
        float mn = dfl[0], mx = dfl[0];
#pragma unroll
        for (int i = 1; i < 16; i++) { mn = fminf(mn, dfl[i]); mx = fmaxf(mx, dfl[i]); }
        const int b = (blockIdx.x * 16) / PP;   // 16 | 2304, no straddle
        atomicMin(&mm[b * 2], __float_as_uint(mn));
        atomicMax(&mm[b * 2 + 1], __float_as_uint(mx));
    }
}

// ---- GroupNorm stats: 64 blocks = (b,g) ----------------------------------
__global__ __launch_bounds__(256) void k_gn(const float* __restrict__ xt,
                                            float* __restrict__ gnb) {
    const int b = blockIdx.x >> 5, g = blockIdx.x & 31;
    const int tid = threadIdx.x;
    float s = 0.f, sq = 0.f;
    for (int p = tid; p < PP; p += 256) {
        float4 v = *(const float4*)(xt + ((size_t)(b * PP + p)) * CH + g * 4);
        s += v.x + v.y + v.z + v.w;
        sq += v.x * v.x + v.y * v.y + v.z * v.z + v.w * v.w;
    }
    __shared__ float rs[256], rq[256];
    rs[tid] = s; rq[tid] = sq;
    __syncthreads();
    for (int st = 128; st; st >>= 1) {
        if (tid < st) { rs[tid] += rs[tid + st]; rq[tid] += rq[tid + st]; }
        __syncthreads();
    }
    if (tid == 0) {
        float mu = rs[0] / 9216.f;
        float var = rq[0] / 9216.f - mu * mu;
        gnb[blockIdx.x * 2] = mu;
        gnb[blockIdx.x * 2 + 1] = 1.f / sqrtf(var + 1e-5f);
    }
}

// ---- main IPG v2: 2x8 pixel tile per block, LDS-staged 14x20 region ------
constexpr int TR = 2, TC = 8;        // tile rows x cols (16 px)
constexpr int RR = TR + 12;          // 14 region rows
constexpr int RC = TC + 12;          // 20 region cols
constexpr int RPX = RR * RC;         // 280 region pixels
constexpr int RST = 20;              // floats per region row (16 ch + 4 pad)
constexpr int NREP = (RPX + 63) / 64;// 5
constexpr int SIMS_W = 172;

__global__ __launch_bounds__(256) void k_main2(const float* __restrict__ xt,
                                               const float* __restrict__ rn,
                                               const float* __restrict__ df,
                                               const unsigned* __restrict__ mm,
                                               const float* __restrict__ gnb,
                                               const float* __restrict__ gamma,
                                               const float* __restrict__ beta,
                                               float* __restrict__ en) {
    __shared__ float region[RPX][RST];     // 22.4 KB, one 16-ch chunk
    __shared__ float sims[16][SIMS_W];     // 11.0 KB
    __shared__ int   gaddr[RPX];           // region px -> global pixel idx
    __shared__ float rnr[RPX];             // region px -> 1/||x||

    const int tid = threadIdx.x;
    const int bid = blockIdx.x;            // 288 blocks
    const int b = bid / 144;
    const int t = bid % 144;
    const int h0 = (t / 6) * TR, w0 = (t % 6) * TC;

    // phase 0: region pixel table (reflection) + norms
    for (int r = tid; r < RPX; r += 256) {
        int ry = r / RC, rx = r % RC;
        int gy = refl(h0 + ry - 6), gx = refl(w0 + rx - 6);
        int pix2 = b * PP + gy * WW + gx;
        gaddr[r] = pix2;
        rnr[r] = rn[pix2];
    }
    __syncthreads();

    const int wv = tid >> 6, lane = tid & 63;
    const int qr = wv >> 1, qc0 = (wv & 1) * 4;  // wave owns px (qr, qc0..qc0+3)

    float acc[NREP][4];
#pragma unroll
    for (int i = 0; i < NREP; i++)
#pragma unroll
        for (int d = 0; d < 4; d++) acc[i][d] = 0.f;

    // phase 1: chunked dot products (8 chunks x 16 channels)
    for (int chk = 0; chk < 8; ++chk) {
        for (int g = tid; g < RPX * 4; g += 256) {
            int r = g >> 2, c4 = g & 3;
            float4 v = *(const float4*)(xt + (size_t)gaddr[r] * CH + chk * 16 + c4 * 4);
            *(float4*)&region[r][c4 * 4] = v;
        }
        __syncthreads();
        float ctr[4][16];
#pragma unroll
        for (int d = 0; d < 4; ++d) {
            int rc = (qr + 6) * RC + (qc0 + d + 6);
#pragma unroll
            for (int c4 = 0; c4 < 4; ++c4) {
                float4 v = *(const float4*)&region[rc][c4 * 4];
                ctr[d][c4 * 4 + 0] = v.x; ctr[d][c4 * 4 + 1] = v.y;
                ctr[d][c4 * 4 + 2] = v.z; ctr[d][c4 * 4 + 3] = v.w;
            }
        }
#pragma unroll
        for (int rep = 0; rep < NREP; ++rep) {
            int r = rep * 64 + lane;
            int rr = r < RPX ? r : 0;
            float rg[16];
#pragma unroll
            for (int c4 = 0; c4 < 4; ++c4) {
                float4 v = *(const float4*)&region[rr][c4 * 4];
                rg[c4 * 4 + 0] = v.x; rg[c4 * 4 + 1] = v.y;
                rg[c4 * 4 + 2] = v.z; rg[c4 * 4 + 3] = v.w;
            }
#pragma unroll
            for (int d = 0; d < 4; ++d)
#pragma unroll
                for (int c = 0; c < 16; ++c)
                    acc[rep][d] += rg[c] * ctr[d][c];
        }
        __syncthreads();
    }

    // phase 1.5: finalize sims into LDS [q][k]
    float rnc[4];
#pragma unroll
    for (int d = 0; d < 4; ++d) rnc[d] = rnr[(qr + 6) * RC + (qc0 + d + 6)];
#pragma unroll
    for (int rep = 0; rep < NREP; ++rep) {
        int r = rep * 64 + lane;
        if (r < RPX) {
            int rrow = r / RC, rcol = r % RC;
            float rrv = rnr[r];
#pragma unroll
            for (int d = 0; d < 4; ++d) {
                int krow = rrow - qr, kcol = rcol - (qc0 + d);
                if ((unsigned)krow < 13u && (unsigned)kcol < 13u) {
                    int q = qr * 8 + qc0 + d;
                    sims[q][krow * 13 + kcol] = acc[rep][d] * rrv * rnc[d];
                }
            }
        }
    }
    __syncthreads();

    // phase 2: per pixel, extract top-cc by (value desc, index asc), fused gather
    const float dmin = __uint_as_float(mm[b * 2]);
    const float dmax = __uint_as_float(mm[b * 2 + 1]);
    for (int d = 0; d < 4; ++d) {
        const int q = qr * 8 + qc0 + d;
        const int pix = b * PP + (h0 + qr) * WW + (w0 + qc0 + d);
        float s0 = sims[q][lane];
        float s1 = (64 + lane < K2) ? sims[q][64 + lane] : -1e30f;
        float s2 = (128 + lane < K2) ? sims[q][128 + lane] : -1e30f;
        const float dn = (df[pix] - dmin) / (dmax - dmin + 1e-8f);
        const int cc = 1 + (int)rintf(dn * 15.f);

        float wsum = 0.f;
        float ax = 0.f, ay = 0.f;
        for (int i = 0; i < cc; ++i) {
            float gm = fmaxf(fmaxf(s0, s1), s2);
#pragma unroll
            for (int sft = 1; sft <= 32; sft <<= 1) gm = fmaxf(gm, __shfl_xor(gm, sft));
            unsigned long long m0 = __ballot(s0 == gm);
            unsigned long long m1 = __ballot(s1 == gm);
            unsigned long long m2 = __ballot(s2 == gm);
            int kw = m0 ? (__ffsll((unsigned long long)m0) - 1)
                   : m1 ? (64 + __ffsll((unsigned long long)m1) - 1)
                        : (128 + __ffsll((unsigned long long)m2) - 1);
            bool me = (lane == (kw & 63));
            s0 = (me && kw < 64) ? -1e30f : s0;
            s1 = (me && kw >= 64 && kw < 128) ? -1e30f : s1;
            s2 = (me && kw >= 128) ? -1e30f : s2;
            float wt = expf(gm);
            wsum += wt;
            int krow = kw / 13, kcol = kw - krow * 13;
            int r = (krow + qr) * RC + (kcol + qc0 + d);
            int p2 = gaddr[r];
            float2 v = ((const float2*)(xt + (size_t)p2 * CH))[lane];
            ax += wt * v.x; ay += wt * v.y;
        }
        const float invw = 1.f / wsum;

        // GroupNorm + residual
        float2 xv = ((const float2*)(xt + (size_t)pix * CH))[lane];
        const int c0 = lane * 2;
        const int g = lane >> 1;
        const float mu = gnb[(b * 32 + g) * 2], rstd = gnb[(b * 32 + g) * 2 + 1];
        float e0 = ax * invw + (xv.x - mu) * rstd * gamma[c0] + beta[c0];
        float e1 = ay * invw + (xv.y - mu) * rstd * gamma[c0 + 1] + beta[c0 + 1];
        ((float2*)(en + (size_t)pix * CH))[lane] = make_float2(e0, e1);
    }
}

// ---- FFN: out = enhanced + (w2 @ relu(w1 @ enhanced + b1) + b2) ----------
__global__ __launch_bounds__(256) void k_ffn(const float* __restrict__ en,
                                             const float* __restrict__ w1,
                                             const float* __restrict__ b1,
                                             const float* __restrict__ w2,
                                             const float* __restrict__ b2,
                                             float* __restrict__ out) {
    __shared__ float elds[16][CH];     // 8 KB
    __shared__ float hlds[16][256];    // 16 KB
    const int tid = threadIdx.x;
    const int p0 = blockIdx.x * 16;    // 288 blocks, 16 px each (no batch straddle)
    const int b = p0 / PP, pb = p0 % PP;
    {
        const float4* src = (const float4*)(en + (size_t)p0 * CH);
        float4* dst = (float4*)&elds[0][0];
#pragma unroll
        for (int r = 0; r < 2; r++) dst[r * 256 + tid] = src[r * 256 + tid];
    }
    __syncthreads();
    {   // h[o] for all 16 px; thread = o
        const int o = tid;
        float acc[16];
#pragma unroll
        for (int i = 0; i < 16; i++) acc[i] = 0.f;
        const float4* wr = (const float4*)(w1 + (size_t)o * CH);
        for (int c4 = 0; c4 < 32; c4++) {
            float4 wvv = wr[c4];
#pragma unroll
            for (int px = 0; px < 16; px++) {
                float4 ev = *(const float4*)&elds[px][c4 * 4];  // LDS broadcast
                acc[px] += wvv.x * ev.x + wvv.y * ev.y + wvv.z * ev.z + wvv.w * ev.w;
            }
        }
        float bv = b1[o];
#pragma unroll
        for (int px = 0; px < 16; px++) hlds[px][o] = fmaxf(acc[px] + bv, 0.f);
    }
    __syncthreads();
    {   // ffn + residual; thread = (c, half)
        const int c = tid & 127, half = tid >> 7;
        const int px0 = half * 8;
        float acc[8];
#pragma unroll
        for (int i = 0; i < 8; i++) acc[i] = 0.f;
        const float4* wr = (const float4*)(w2 + (size_t)c * 256);
        for (int o4 = 0; o4 < 64; o4++) {
            float4 wvv = wr[o4];
#pragma unroll
            for (int i = 0; i < 8; i++) {
                float4 hv = *(const float4*)&hlds[px0 + i][o4 * 4];  // LDS broadcast
                acc[i] += wvv.x * hv.x + wvv.y * hv.y + wvv.z * hv.z + wvv.w * hv.w;
            }
        }
        float bv = b2[c];
        float* obase = out + ((size_t)(b * CH + c)) * PP + pb + px0;
#pragma unroll
        for (int r = 0; r < 2; r++) {
            float4 v;
            v.x = elds[px0 + r * 4 + 0][c] + acc[r * 4 + 0] + bv;
            v.y = elds[px0 + r * 4 + 1][c] + acc[r * 4 + 1] + bv;
            v.z = elds[px0 + r * 4 + 2][c] + acc[r * 4 + 2] + bv;
            v.w = elds[px0 + r * 4 + 3][c] + acc[r * 4 + 3] + bv;
            *(float4*)(obase + r * 4) = v;
        }
    }
}

extern "C" void kernel_launch(void* const* d_in, const int* in_sizes, int n_in,
                              void* d_out, int out_size, void* d_ws, size_t ws_size,
                              hipStream_t stream) {
    (void)in_sizes; (void)n_in; (void)out_size;
    if (ws_size < WS_FLOATS * sizeof(float)) return;  // would corrupt; fail visibly

    const float* x     = (const float*)d_in[0];
    const float* gamma = (const float*)d_in[1];
    const float* beta  = (const float*)d_in[2];
    const float* w1    = (const float*)d_in[3];
    const float* b1    = (const float*)d_in[4];
    const float* w2    = (const float*)d_in[5];
    const float* b2    = (const float*)d_in[6];
    float* ws = (float*)d_ws;
    float* xt   = ws + OFF_XT;
    float* en   = ws + OFF_EN;
    float* xdt  = ws + OFF_XD;
    float* rn   = ws + OFF_RN;
    float* df   = ws + OFF_DF;
    unsigned* mm = (unsigned*)(ws + OFF_MM);
    float* gnb  = ws + OFF_GN;
    float* out  = (float*)d_out;

    hipLaunchKernelGGL(k_tr,    dim3(72),   dim3(256), 0, stream, x, xt, mm);
    hipLaunchKernelGGL(k_down,  dim3(144),  dim3(256), 0, stream, xt, xdt);
    hipLaunchKernelGGL(k_df,    dim3(288),  dim3(256), 0, stream, xt, xdt, df, rn, mm);
    hipLaunchKernelGGL(k_gn,    dim3(64),   dim3(256), 0, stream, xt, gnb);
    hipLaunchKernelGGL(k_main2, dim3(288),  dim3(256), 0, stream, xt, rn, df, mm, gnb, gamma, beta, en);
    hipLaunchKernelGGL(k_ffn,   dim3(288),  dim3(256), 0, stream, en, w1, b1, w2, b2, out);
}